// Round 1
// baseline (890.137 us; speedup 1.0000x reference)
//
#include <hip/hip_runtime.h>

typedef _Float16 half8 __attribute__((ext_vector_type(8)));
typedef _Float16 half4v __attribute__((ext_vector_type(4)));
typedef float f32x4 __attribute__((ext_vector_type(4)));
typedef unsigned int u32;

#define LDH 136   // fp16 row stride for h16/agg16 (+8 halves pad -> 4-word bank rotate)

__device__ __forceinline__ void async16(void* lds, const void* g) {
  __builtin_amdgcn_global_load_lds(
      (const __attribute__((address_space(1))) u32*)g,
      (__attribute__((address_space(3))) u32*)lds, 16, 0, 0);
}

// --------- weight prep: fp32 [k][n] -> fp16 MFMA-fragment-ordered images -------
// w1img @0      (65536 h): 16 half-stages x 8 groups x 64 lanes x 8 halves
// w2img @65536  (32768 h): 8 nc-chunks x 8 ntiles x 64 lanes x 8
// nw1img @98304, nw2img @163840 : same layouts
__global__ void prep_weights(const float* __restrict__ ew1,
                             const float* __restrict__ ew2,
                             const float* __restrict__ nw1,
                             const float* __restrict__ nw2,
                             _Float16* __restrict__ wz) {
  int o = blockIdx.x * 256 + threadIdx.x;
  if (o < 65536) {
    int s = o >> 12, r = o & 4095;
    int gs = r >> 9, lane = (r >> 3) & 63, j = r & 7;
    int k = ((s & 1) * 4 + (gs >> 1)) * 32 + (lane >> 4) * 8 + j;
    int n = (s >> 1) * 32 + (gs & 1) * 16 + (lane & 15);
    wz[o] = (_Float16)ew1[k * 256 + n];
  } else if (o < 98304) {
    int o2 = o - 65536;
    int nc = o2 >> 12, r = o2 & 4095;
    int nt2 = r >> 9, lane = (r >> 3) & 63, j = r & 7;
    int k = nc * 32 + (lane >> 4) * 8 + j;
    int n = nt2 * 16 + (lane & 15);
    wz[o] = (_Float16)ew2[k * 128 + n];
  } else if (o < 163840) {
    int o2 = o - 98304;
    int s = o2 >> 12, r = o2 & 4095;
    int gs = r >> 9, lane = (r >> 3) & 63, j = r & 7;
    int k = ((s & 1) * 4 + (gs >> 1)) * 32 + (lane >> 4) * 8 + j;
    int n = (s >> 1) * 32 + (gs & 1) * 16 + (lane & 15);
    wz[o] = (_Float16)nw1[k * 256 + n];
  } else if (o < 196608) {
    int o2 = o - 163840;
    int nc = o2 >> 12, r = o2 & 4095;
    int nt2 = r >> 9, lane = (r >> 3) & 63, j = r & 7;
    int k = nc * 32 + (lane >> 4) * 8 + j;
    int n = nt2 * 16 + (lane & 15);
    wz[o] = (_Float16)nw2[k * 128 + n];
  }
}

// --------- fused layer: 4 batches/block, 4 waves, async dbuf weight staging -----
__global__ __launch_bounds__(256, 2)
void fused_graph_layer(const float* __restrict__ h, const float* __restrict__ xy,
                       const int* __restrict__ jmask, const int* __restrict__ eidx,
                       const float* __restrict__ ew1,   // rel rows 256,257
                       const float* __restrict__ eb1, const float* __restrict__ eb2,
                       const float* __restrict__ nb1, const float* __restrict__ nb2,
                       const float* __restrict__ gamma, const float* __restrict__ beta,
                       const _Float16* __restrict__ wz,
                       float* __restrict__ out) {
  __shared__ _Float16 sh_h16[68 * LDH];                       // 18496 B
  __shared__ _Float16 sh_agg16[68 * LDH];                     // 18496 B
  __shared__ char uni[35904] __attribute__((aligned(16)));    // p0|p1|myC / agg32 / ost
  __shared__ float sh_rel[256];
  __shared__ float sh_valid[128];
  __shared__ float sh_denom[68], sh_hasn[68], sh_maskf[68];
  __shared__ int   sh_edge[64];

  const int tid  = threadIdx.x;
  const int wave = tid >> 6;
  const int lane = tid & 63;
  const int ln   = lane & 15;
  const int quad = lane >> 4;
  const int n0   = blockIdx.x * 4;
  const size_t hbase = (size_t)n0 * 2176;
  const f32x4 vzero = {0.f, 0.f, 0.f, 0.f};

  _Float16* p0  = (_Float16*)uni;                 // 4096 h (8 KB)
  _Float16* p1  = (_Float16*)(uni + 8192);        // 4096 h
  _Float16* myC = (_Float16*)(uni + 16384) + wave * 1280;  // 32 x 40 h per wave

  const _Float16* w1img  = wz;
  const _Float16* w2img  = wz + 65536;
  const _Float16* nw1img = wz + 98304;
  const _Float16* nw2img = wz + 163840;
  const float* w1r0 = ew1 + 256 * 256;
  const float* w1r1 = ew1 + 257 * 256;

  // issue edge stage 0 ASAP (lands during h staging)
  {
    const _Float16* src = w1img + (2 * wave) * 512 + lane * 8;
    async16(p0 + (2 * wave) * 512, src);
    async16(p0 + (2 * wave + 1) * 512, src + 512);
  }

  // ---- stage h -> fp16 LDS; edges; mask ----
  if (tid < 64) sh_edge[tid] = eidx[tid];
  if (tid < 68) sh_maskf[tid] = (float)jmask[n0 * 17 + tid];
  for (int i = tid; i < 2176; i += 256) {
    const float4 hv = ((const float4*)(h + hbase))[i];
    int q = i << 2;
    int gv = q >> 7, d = q & 127;
    half4v hq = { (_Float16)hv.x, (_Float16)hv.y, (_Float16)hv.z, (_Float16)hv.w };
    *(half4v*)&sh_h16[gv * LDH + d] = hq;
  }
  __syncthreads();                                   // S1
  if (tid < 128) {
    int g = tid >> 5, e = tid & 31;
    int dv = sh_edge[2 * e], sv = sh_edge[2 * e + 1];
    const float* xyb = xy + (size_t)(n0 + g) * 34;
    sh_rel[2 * tid]     = xyb[2 * sv]     - xyb[2 * dv];
    sh_rel[2 * tid + 1] = xyb[2 * sv + 1] - xyb[2 * dv + 1];
    sh_valid[tid] = sh_maskf[g * 17 + dv] * sh_maskf[g * 17 + sv];
  }
  __syncthreads();                                   // S2
  if (tid < 68) {
    int g = tid / 17, v = tid - g * 17;
    float den = 0.f;
    for (int e = 0; e < 32; ++e)
      if (sh_edge[2 * e] == v) den += sh_valid[g * 32 + e];
    sh_denom[tid] = den;
    sh_hasn[tid]  = den > 0.f ? 1.f : 0.f;
  }

  // ---- preload edge A fragments into registers (read h16 once) ----
  int baseT[2], baseS[2];
  #pragma unroll
  for (int mi = 0; mi < 2; ++mi) {
    int eL = mi * 16 + ln;
    baseT[mi] = (wave * 17 + sh_edge[2 * eL]) * LDH;
    baseS[mi] = (wave * 17 + sh_edge[2 * eL + 1]) * LDH;
  }
  half8 af[2][8];
  #pragma unroll
  for (int mi = 0; mi < 2; ++mi)
    #pragma unroll
    for (int ks = 0; ks < 8; ++ks)
      af[mi][ks] = (ks < 4)
          ? *(const half8*)&sh_h16[baseT[mi] + ks * 32 + quad * 8]
          : *(const half8*)&sh_h16[baseS[mi] + (ks - 4) * 32 + quad * 8];

  // ================= EDGE PHASE =================
  f32x4 acc2[2][8];
  #pragma unroll
  for (int i = 0; i < 2; ++i)
    #pragma unroll
    for (int j = 0; j < 8; ++j) acc2[i][j] = vzero;

  for (int nc = 0; nc < 8; ++nc) {
    __syncthreads();                                 // even stage 2nc ready in p0
    {
      const _Float16* src = w1img + (size_t)(2 * nc + 1) * 4096 + (2 * wave) * 512 + lane * 8;
      async16(p1 + (2 * wave) * 512, src);
      async16(p1 + (2 * wave + 1) * 512, src + 512);
    }
    half8 b2f[8];
    #pragma unroll
    for (int t = 0; t < 8; ++t)
      b2f[t] = *(const half8*)(w2img + nc * 4096 + t * 512 + lane * 8);
    float ebv[2], r0v[2], r1v[2];
    #pragma unroll
    for (int nt = 0; nt < 2; ++nt) {
      int J = nc * 32 + nt * 16 + ln;
      ebv[nt] = eb1[J]; r0v[nt] = w1r0[J]; r1v[nt] = w1r1[J];
    }
    f32x4 acc1[2][2];
    #pragma unroll
    for (int i = 0; i < 2; ++i) { acc1[i][0] = vzero; acc1[i][1] = vzero; }

    #pragma unroll
    for (int ksl = 0; ksl < 4; ++ksl) {
      half8 bf0 = *(const half8*)&p0[(ksl * 2 + 0) * 512 + lane * 8];
      half8 bf1 = *(const half8*)&p0[(ksl * 2 + 1) * 512 + lane * 8];
      #pragma unroll
      for (int mi = 0; mi < 2; ++mi) {
        acc1[mi][0] = __builtin_amdgcn_mfma_f32_16x16x32_f16(af[mi][ksl], bf0, acc1[mi][0], 0, 0, 0);
        acc1[mi][1] = __builtin_amdgcn_mfma_f32_16x16x32_f16(af[mi][ksl], bf1, acc1[mi][1], 0, 0, 0);
      }
    }
    __syncthreads();                                 // odd stage 2nc+1 ready in p1
    if (nc < 7) {
      const _Float16* src = w1img + (size_t)(2 * nc + 2) * 4096 + (2 * wave) * 512 + lane * 8;
      async16(p0 + (2 * wave) * 512, src);
      async16(p0 + (2 * wave + 1) * 512, src + 512);
    }
    #pragma unroll
    for (int ksl = 0; ksl < 4; ++ksl) {
      half8 bf0 = *(const half8*)&p1[(ksl * 2 + 0) * 512 + lane * 8];
      half8 bf1 = *(const half8*)&p1[(ksl * 2 + 1) * 512 + lane * 8];
      #pragma unroll
      for (int mi = 0; mi < 2; ++mi) {
        acc1[mi][0] = __builtin_amdgcn_mfma_f32_16x16x32_f16(af[mi][4 + ksl], bf0, acc1[mi][0], 0, 0, 0);
        acc1[mi][1] = __builtin_amdgcn_mfma_f32_16x16x32_f16(af[mi][4 + ksl], bf1, acc1[mi][1], 0, 0, 0);
      }
    }
    // epilogue1: bias + rel rank-2 + relu -> per-wave myC (fp16)
    #pragma unroll
    for (int nt = 0; nt < 2; ++nt)
      #pragma unroll
      for (int mi = 0; mi < 2; ++mi)
        #pragma unroll
        for (int r = 0; r < 4; ++r) {
          int R = wave * 32 + mi * 16 + quad * 4 + r;
          float2 rr = *(const float2*)&sh_rel[2 * R];
          float val = acc1[mi][nt][r] + ebv[nt] + rr.x * r0v[nt] + rr.y * r1v[nt];
          myC[(mi * 16 + quad * 4 + r) * 40 + nt * 16 + ln] = (_Float16)fmaxf(val, 0.f);
        }
    // GEMM2 partial-K (same wave wrote myC; lgkmcnt handles dep)
    #pragma unroll
    for (int mi = 0; mi < 2; ++mi) {
      half8 a2 = *(const half8*)&myC[(mi * 16 + ln) * 40 + quad * 8];
      #pragma unroll
      for (int nt2 = 0; nt2 < 8; ++nt2)
        acc2[mi][nt2] = __builtin_amdgcn_mfma_f32_16x16x32_f16(a2, b2f[nt2], acc2[mi][nt2], 0, 0, 0);
    }
  }

  // ---- aggregate: zero agg32, LDS atomics, normalize -> agg16 ----
  __syncthreads();                                   // p/myC reads done
  float* agg32 = (float*)uni;
  for (int i = tid; i < 8976; i += 256) agg32[i] = 0.f;
  float eb2v[8];
  #pragma unroll
  for (int t = 0; t < 8; ++t) eb2v[t] = eb2[t * 16 + ln];
  int dstv[2][4];
  float vldv[2][4];
  #pragma unroll
  for (int mi = 0; mi < 2; ++mi)
    #pragma unroll
    for (int r = 0; r < 4; ++r) {
      int e = mi * 16 + quad * 4 + r;
      dstv[mi][r] = (wave * 17 + sh_edge[2 * e]) * 132;
      vldv[mi][r] = sh_valid[wave * 32 + e];
    }
  __syncthreads();
  #pragma unroll
  for (int nt2 = 0; nt2 < 8; ++nt2) {
    int d = nt2 * 16 + ln;
    #pragma unroll
    for (int mi = 0; mi < 2; ++mi)
      #pragma unroll
      for (int r = 0; r < 4; ++r) {
        float msg = (acc2[mi][nt2][r] + eb2v[nt2]) * vldv[mi][r];
        atomicAdd(&agg32[dstv[mi][r] + d], msg);
      }
  }
  __syncthreads();
  for (int i = tid; i < 8704; i += 256) {
    int gv = i >> 7, d = i & 127;
    sh_agg16[gv * LDH + d] = (_Float16)(agg32[gv * 132 + d] / fmaxf(sh_denom[gv], 1.f));
  }
  __syncthreads();                                   // agg16 visible; uni free

  // ================= NODE PHASE =================
  {
    const _Float16* src = nw1img + (2 * wave) * 512 + lane * 8;
    async16(p0 + (2 * wave) * 512, src);
    async16(p0 + (2 * wave + 1) * 512, src + 512);
  }
  const int Rn = wave * 16 + ln;                     // < 64, always valid
  half8 afn0[8];
  #pragma unroll
  for (int ks = 0; ks < 8; ++ks)
    afn0[ks] = (ks < 4)
        ? *(const half8*)&sh_h16[Rn * LDH + ks * 32 + quad * 8]
        : *(const half8*)&sh_agg16[Rn * LDH + (ks - 4) * 32 + quad * 8];
  half8 afn1[8];                                     // wave 0: tile 4 (rows 64..67)
  if (wave == 0) {
    const int Rx = (64 + ln < 68) ? 64 + ln : 67;
    #pragma unroll
    for (int ks = 0; ks < 8; ++ks)
      afn1[ks] = (ks < 4)
          ? *(const half8*)&sh_h16[Rx * LDH + ks * 32 + quad * 8]
          : *(const half8*)&sh_agg16[Rx * LDH + (ks - 4) * 32 + quad * 8];
  }

  f32x4 acc4a[8], acc4b[8];
  #pragma unroll
  for (int j = 0; j < 8; ++j) { acc4a[j] = vzero; acc4b[j] = vzero; }

  for (int nc = 0; nc < 8; ++nc) {
    __syncthreads();
    {
      const _Float16* src = nw1img + (size_t)(2 * nc + 1) * 4096 + (2 * wave) * 512 + lane * 8;
      async16(p1 + (2 * wave) * 512, src);
      async16(p1 + (2 * wave + 1) * 512, src + 512);
    }
    half8 b2n[8];
    #pragma unroll
    for (int t = 0; t < 8; ++t)
      b2n[t] = *(const half8*)(nw2img + nc * 4096 + t * 512 + lane * 8);
    float nbv[2];
    #pragma unroll
    for (int nt = 0; nt < 2; ++nt) nbv[nt] = nb1[nc * 32 + nt * 16 + ln];

    f32x4 acc3a[2], acc3b[2];
    acc3a[0] = vzero; acc3a[1] = vzero; acc3b[0] = vzero; acc3b[1] = vzero;

    #pragma unroll
    for (int ksl = 0; ksl < 4; ++ksl) {
      half8 bf0 = *(const half8*)&p0[(ksl * 2 + 0) * 512 + lane * 8];
      half8 bf1 = *(const half8*)&p0[(ksl * 2 + 1) * 512 + lane * 8];
      acc3a[0] = __builtin_amdgcn_mfma_f32_16x16x32_f16(afn0[ksl], bf0, acc3a[0], 0, 0, 0);
      acc3a[1] = __builtin_amdgcn_mfma_f32_16x16x32_f16(afn0[ksl], bf1, acc3a[1], 0, 0, 0);
      if (wave == 0) {
        acc3b[0] = __builtin_amdgcn_mfma_f32_16x16x32_f16(afn1[ksl], bf0, acc3b[0], 0, 0, 0);
        acc3b[1] = __builtin_amdgcn_mfma_f32_16x16x32_f16(afn1[ksl], bf1, acc3b[1], 0, 0, 0);
      }
    }
    __syncthreads();
    if (nc < 7) {
      const _Float16* src = nw1img + (size_t)(2 * nc + 2) * 4096 + (2 * wave) * 512 + lane * 8;
      async16(p0 + (2 * wave) * 512, src);
      async16(p0 + (2 * wave + 1) * 512, src + 512);
    }
    #pragma unroll
    for (int ksl = 0; ksl < 4; ++ksl) {
      half8 bf0 = *(const half8*)&p1[(ksl * 2 + 0) * 512 + lane * 8];
      half8 bf1 = *(const half8*)&p1[(ksl * 2 + 1) * 512 + lane * 8];
      acc3a[0] = __builtin_amdgcn_mfma_f32_16x16x32_f16(afn0[4 + ksl], bf0, acc3a[0], 0, 0, 0);
      acc3a[1] = __builtin_amdgcn_mfma_f32_16x16x32_f16(afn0[4 + ksl], bf1, acc3a[1], 0, 0, 0);
      if (wave == 0) {
        acc3b[0] = __builtin_amdgcn_mfma_f32_16x16x32_f16(afn1[4 + ksl], bf0, acc3b[0], 0, 0, 0);
        acc3b[1] = __builtin_amdgcn_mfma_f32_16x16x32_f16(afn1[4 + ksl], bf1, acc3b[1], 0, 0, 0);
      }
    }
    // relu -> myC, then GEMM4 partial-K
    #pragma unroll
    for (int nt = 0; nt < 2; ++nt)
      #pragma unroll
      for (int r = 0; r < 4; ++r)
        myC[(quad * 4 + r) * 40 + nt * 16 + ln] = (_Float16)fmaxf(acc3a[nt][r] + nbv[nt], 0.f);
    if (wave == 0) {
      #pragma unroll
      for (int nt = 0; nt < 2; ++nt)
        #pragma unroll
        for (int r = 0; r < 4; ++r)
          myC[(16 + quad * 4 + r) * 40 + nt * 16 + ln] = (_Float16)fmaxf(acc3b[nt][r] + nbv[nt], 0.f);
    }
    {
      half8 a2 = *(const half8*)&myC[ln * 40 + quad * 8];
      #pragma unroll
      for (int nt2 = 0; nt2 < 8; ++nt2)
        acc4a[nt2] = __builtin_amdgcn_mfma_f32_16x16x32_f16(a2, b2n[nt2], acc4a[nt2], 0, 0, 0);
    }
    if (wave == 0) {
      half8 a2b = *(const half8*)&myC[(16 + ln) * 40 + quad * 8];
      #pragma unroll
      for (int nt2 = 0; nt2 < 8; ++nt2)
        acc4b[nt2] = __builtin_amdgcn_mfma_f32_16x16x32_f16(a2b, b2n[nt2], acc4b[nt2], 0, 0, 0);
    }
  }

  // ---- final epilogue: residual + LayerNorm + mask -> ost -> coalesced store ---
  float gam[8], bet[8], nb2v[8];
  #pragma unroll
  for (int nt2 = 0; nt2 < 8; ++nt2) {
    int d = nt2 * 16 + ln;
    gam[nt2] = gamma[d]; bet[nt2] = beta[d]; nb2v[nt2] = nb2[d];
  }
  __syncthreads();                                   // node LDS reads done; uni -> ost
  float* ost = (float*)uni;
  {
    float xv[8][4];
    #pragma unroll
    for (int nt2 = 0; nt2 < 8; ++nt2) {
      int d = nt2 * 16 + ln;
      #pragma unroll
      for (int r = 0; r < 4; ++r) {
        int R = wave * 16 + quad * 4 + r;
        xv[nt2][r] = (float)sh_h16[R * LDH + d] + (acc4a[nt2][r] + nb2v[nt2]) * sh_hasn[R];
      }
    }
    #pragma unroll
    for (int r = 0; r < 4; ++r) {
      float s = 0.f, s2 = 0.f;
      #pragma unroll
      for (int nt2 = 0; nt2 < 8; ++nt2) { float x = xv[nt2][r]; s += x; s2 += x * x; }
      #pragma unroll
      for (int m = 1; m < 16; m <<= 1) { s += __shfl_xor(s, m, 64); s2 += __shfl_xor(s2, m, 64); }
      float mu = s * (1.f / 128.f);
      float var = s2 * (1.f / 128.f) - mu * mu;
      float rstd = rsqrtf(var + 1e-5f);
      int R = wave * 16 + quad * 4 + r;
      float mk = sh_maskf[R];
      #pragma unroll
      for (int nt2 = 0; nt2 < 8; ++nt2) {
        int d = nt2 * 16 + ln;
        ost[R * 132 + d] = ((xv[nt2][r] - mu) * rstd * gam[nt2] + bet[nt2]) * mk;
      }
    }
  }
  if (wave == 0) {                                   // tile 4: rows 64..67
    float xv[8][4];
    #pragma unroll
    for (int nt2 = 0; nt2 < 8; ++nt2) {
      int d = nt2 * 16 + ln;
      #pragma unroll
      for (int r = 0; r < 4; ++r) {
        int R = 64 + quad * 4 + r;
        int Rc = R < 68 ? R : 67;
        xv[nt2][r] = (float)sh_h16[Rc * LDH + d] + (acc4b[nt2][r] + nb2v[nt2]) * sh_hasn[Rc];
      }
    }
    #pragma unroll
    for (int r = 0; r < 4; ++r) {
      float s = 0.f, s2 = 0.f;
      #pragma unroll
      for (int nt2 = 0; nt2 < 8; ++nt2) { float x = xv[nt2][r]; s += x; s2 += x * x; }
      #pragma unroll
      for (int m = 1; m < 16; m <<= 1) { s += __shfl_xor(s, m, 64); s2 += __shfl_xor(s2, m, 64); }
      float mu = s * (1.f / 128.f);
      float var = s2 * (1.f / 128.f) - mu * mu;
      float rstd = rsqrtf(var + 1e-5f);
      int R = 64 + quad * 4 + r;
      if (R < 68) {
        float mk = sh_maskf[R];
        #pragma unroll
        for (int nt2 = 0; nt2 < 8; ++nt2) {
          int d = nt2 * 16 + ln;
          ost[R * 132 + d] = ((xv[nt2][r] - mu) * rstd * gam[nt2] + bet[nt2]) * mk;
        }
      }
    }
  }
  __syncthreads();
  for (int i = tid; i < 8704; i += 256)
    out[hbase + i] = ost[(i >> 7) * 132 + (i & 127)];
}

extern "C" void kernel_launch(void* const* d_in, const int* in_sizes, int n_in,
                              void* d_out, int out_size, void* d_ws, size_t ws_size,
                              hipStream_t stream) {
  const float* h     = (const float*)d_in[0];
  const float* xy    = (const float*)d_in[1];
  const int*   jm    = (const int*)d_in[2];
  const int*   ei    = (const int*)d_in[3];
  const float* ew1   = (const float*)d_in[4];
  const float* eb1   = (const float*)d_in[5];
  const float* ew2   = (const float*)d_in[6];
  const float* eb2   = (const float*)d_in[7];
  const float* nw1   = (const float*)d_in[8];
  const float* nb1   = (const float*)d_in[9];
  const float* nw2   = (const float*)d_in[10];
  const float* nb2   = (const float*)d_in[11];
  const float* gamma = (const float*)d_in[12];
  const float* beta  = (const float*)d_in[13];
  _Float16* wz = (_Float16*)d_ws;

  prep_weights<<<768, 256, 0, stream>>>(ew1, ew2, nw1, nw2, wz);
  fused_graph_layer<<<4096, 256, 0, stream>>>(h, xy, jm, ei, ew1, eb1, eb2,
                                              nb1, nb2, gamma, beta, wz,
                                              (float*)d_out);
}

// Round 2
// 632.317 us; speedup vs baseline: 1.4077x; 1.4077x over previous
//
#include <hip/hip_runtime.h>

typedef _Float16 half8 __attribute__((ext_vector_type(8)));
typedef _Float16 half4v __attribute__((ext_vector_type(4)));
typedef float f32x4 __attribute__((ext_vector_type(4)));
typedef unsigned int u32;

#define LDH 136   // fp16 row stride for h16/agg16 (+8 halves pad -> 4-word bank rotate)

// --------- weight prep: fp32 [k][n] -> fp16 MFMA-fragment-ordered images -------
// w1img @0      (65536 h): 16 half-stages x 8 groups x 64 lanes x 8 halves
// w2img @65536  (32768 h): 8 nc-chunks x 8 ntiles x 64 lanes x 8
// nw1img @98304, nw2img @163840 : same layouts
__global__ void prep_weights(const float* __restrict__ ew1,
                             const float* __restrict__ ew2,
                             const float* __restrict__ nw1,
                             const float* __restrict__ nw2,
                             _Float16* __restrict__ wz) {
  int o = blockIdx.x * 256 + threadIdx.x;
  if (o < 65536) {
    int s = o >> 12, r = o & 4095;
    int gs = r >> 9, lane = (r >> 3) & 63, j = r & 7;
    int k = ((s & 1) * 4 + (gs >> 1)) * 32 + (lane >> 4) * 8 + j;
    int n = (s >> 1) * 32 + (gs & 1) * 16 + (lane & 15);
    wz[o] = (_Float16)ew1[k * 256 + n];
  } else if (o < 98304) {
    int o2 = o - 65536;
    int nc = o2 >> 12, r = o2 & 4095;
    int nt2 = r >> 9, lane = (r >> 3) & 63, j = r & 7;
    int k = nc * 32 + (lane >> 4) * 8 + j;
    int n = nt2 * 16 + (lane & 15);
    wz[o] = (_Float16)ew2[k * 128 + n];
  } else if (o < 163840) {
    int o2 = o - 98304;
    int s = o2 >> 12, r = o2 & 4095;
    int gs = r >> 9, lane = (r >> 3) & 63, j = r & 7;
    int k = ((s & 1) * 4 + (gs >> 1)) * 32 + (lane >> 4) * 8 + j;
    int n = (s >> 1) * 32 + (gs & 1) * 16 + (lane & 15);
    wz[o] = (_Float16)nw1[k * 256 + n];
  } else if (o < 196608) {
    int o2 = o - 163840;
    int nc = o2 >> 12, r = o2 & 4095;
    int nt2 = r >> 9, lane = (r >> 3) & 63, j = r & 7;
    int k = nc * 32 + (lane >> 4) * 8 + j;
    int n = nt2 * 16 + (lane & 15);
    wz[o] = (_Float16)nw2[k * 128 + n];
  }
}

// --------- fused layer: 4 batches/block, 4 waves, barrier-free GEMM loops ------
// Weights are read directly global->VGPR (L2-resident, no LDS staging, no
// barriers in the K/N loops). Aggregation is a per-wave gather-MFMA
// (S[17x32] @ msg[32x128]) instead of LDS atomics. 5 barriers total.
__global__ __launch_bounds__(256, 2)
void fused_graph_layer(const float* __restrict__ h, const float* __restrict__ xy,
                       const int* __restrict__ jmask, const int* __restrict__ eidx,
                       const float* __restrict__ ew1,   // rel rows 256,257
                       const float* __restrict__ eb1, const float* __restrict__ eb2,
                       const float* __restrict__ nb1, const float* __restrict__ nb2,
                       const float* __restrict__ gamma, const float* __restrict__ beta,
                       const _Float16* __restrict__ wz,
                       float* __restrict__ out) {
  __shared__ _Float16 sh_h16[68 * LDH];                       // 18496 B
  __shared__ _Float16 sh_agg16[68 * LDH];                     // 18496 B
  __shared__ char uni[36864] __attribute__((aligned(16)));    // per-wave myC/msgT ; ost
  __shared__ float sh_rel[256];
  __shared__ float sh_valid[128];
  __shared__ float sh_dn[80];                                 // per-wave denom [4][20]
  __shared__ float sh_hasn[68], sh_maskf[68];
  __shared__ int   sh_edge[64];

  const int tid  = threadIdx.x;
  const int wave = tid >> 6;
  const int lane = tid & 63;
  const int ln   = lane & 15;
  const int quad = lane >> 4;
  const int n0   = blockIdx.x * 4;
  const size_t hbase = (size_t)n0 * 2176;
  const f32x4 vzero = {0.f, 0.f, 0.f, 0.f};

  _Float16* ws = (_Float16*)(uni + wave * 9216);  // per-wave scratch: myC (32x40) / msgT (128x36)

  const _Float16* w1img  = wz;
  const _Float16* w2img  = wz + 65536;
  const _Float16* nw1img = wz + 98304;
  const _Float16* nw2img = wz + 163840;
  const float* w1r0 = ew1 + 256 * 256;
  const float* w1r1 = ew1 + 257 * 256;

  // ---- stage h -> fp16 LDS; edges; mask ----
  if (tid < 64) sh_edge[tid] = eidx[tid];
  if (tid < 68) sh_maskf[tid] = (float)jmask[n0 * 17 + tid];
  for (int i = tid; i < 2176; i += 256) {
    const float4 hv = ((const float4*)(h + hbase))[i];
    int q = i << 2;
    int gv = q >> 7, d = q & 127;
    half4v hq = { (_Float16)hv.x, (_Float16)hv.y, (_Float16)hv.z, (_Float16)hv.w };
    *(half4v*)&sh_h16[gv * LDH + d] = hq;
  }
  __syncthreads();                                   // S1: h16, edges, maskf
  if (tid < 128) {
    int g = tid >> 5, e = tid & 31;
    int dv = sh_edge[2 * e], sv = sh_edge[2 * e + 1];
    const float* xyb = xy + (size_t)(n0 + g) * 34;
    sh_rel[2 * tid]     = xyb[2 * sv]     - xyb[2 * dv];
    sh_rel[2 * tid + 1] = xyb[2 * sv + 1] - xyb[2 * dv + 1];
    sh_valid[tid] = sh_maskf[g * 17 + dv] * sh_maskf[g * 17 + sv];
  }
  __syncthreads();                                   // S2: rel, valid

  // ---- per-wave denominators (no cross-wave dep) ----
  if (lane < 17) {
    float den = 0.f;
    for (int e = 0; e < 32; ++e)
      den += (sh_edge[2 * e] == lane) ? sh_valid[wave * 32 + e] : 0.f;
    sh_dn[wave * 20 + lane] = den;
    sh_hasn[wave * 17 + lane] = den > 0.f ? 1.f : 0.f;
  }

  // ---- preload edge A fragments into registers (read h16 once) ----
  int baseT[2], baseS[2];
  #pragma unroll
  for (int mi = 0; mi < 2; ++mi) {
    int eL = mi * 16 + ln;
    baseT[mi] = (wave * 17 + sh_edge[2 * eL]) * LDH;
    baseS[mi] = (wave * 17 + sh_edge[2 * eL + 1]) * LDH;
  }
  half8 af[2][8];
  #pragma unroll
  for (int mi = 0; mi < 2; ++mi)
    #pragma unroll
    for (int ks = 0; ks < 8; ++ks)
      af[mi][ks] = (ks < 4)
          ? *(const half8*)&sh_h16[baseT[mi] + ks * 32 + quad * 8]
          : *(const half8*)&sh_h16[baseS[mi] + (ks - 4) * 32 + quad * 8];

  // ================= EDGE PHASE (no barriers) =================
  f32x4 acc2[2][8];
  #pragma unroll
  for (int i = 0; i < 2; ++i)
    #pragma unroll
    for (int j = 0; j < 8; ++j) acc2[i][j] = vzero;

  for (int nc = 0; nc < 8; ++nc) {
    half8 b2f[8];
    #pragma unroll
    for (int t = 0; t < 8; ++t)
      b2f[t] = *(const half8*)(w2img + nc * 4096 + t * 512 + lane * 8);
    float ebv[2], r0v[2], r1v[2];
    #pragma unroll
    for (int nt = 0; nt < 2; ++nt) {
      int J = nc * 32 + nt * 16 + ln;
      ebv[nt] = eb1[J]; r0v[nt] = w1r0[J]; r1v[nt] = w1r1[J];
    }
    f32x4 acc1[2][2];
    #pragma unroll
    for (int i = 0; i < 2; ++i) { acc1[i][0] = vzero; acc1[i][1] = vzero; }

    #pragma unroll
    for (int kc = 0; kc < 8; ++kc) {
      const _Float16* wb = w1img + (size_t)(nc * 2 + (kc >> 2)) * 4096
                                 + ((kc & 3) * 2) * 512 + lane * 8;
      half8 bf0 = *(const half8*)wb;
      half8 bf1 = *(const half8*)(wb + 512);
      #pragma unroll
      for (int mi = 0; mi < 2; ++mi) {
        acc1[mi][0] = __builtin_amdgcn_mfma_f32_16x16x32_f16(af[mi][kc], bf0, acc1[mi][0], 0, 0, 0);
        acc1[mi][1] = __builtin_amdgcn_mfma_f32_16x16x32_f16(af[mi][kc], bf1, acc1[mi][1], 0, 0, 0);
      }
    }
    // epilogue1: bias + rel rank-2 + relu -> per-wave myC (fp16)
    #pragma unroll
    for (int nt = 0; nt < 2; ++nt)
      #pragma unroll
      for (int mi = 0; mi < 2; ++mi)
        #pragma unroll
        for (int r = 0; r < 4; ++r) {
          int R = wave * 32 + mi * 16 + quad * 4 + r;
          float2 rr = *(const float2*)&sh_rel[2 * R];
          float val = acc1[mi][nt][r] + ebv[nt] + rr.x * r0v[nt] + rr.y * r1v[nt];
          ws[(mi * 16 + quad * 4 + r) * 40 + nt * 16 + ln] = (_Float16)fmaxf(val, 0.f);
        }
    // GEMM2 partial-K (same wave wrote myC; lgkmcnt handles dep)
    #pragma unroll
    for (int mi = 0; mi < 2; ++mi) {
      half8 a2 = *(const half8*)&ws[(mi * 16 + ln) * 40 + quad * 8];
      #pragma unroll
      for (int nt2 = 0; nt2 < 8; ++nt2)
        acc2[mi][nt2] = __builtin_amdgcn_mfma_f32_16x16x32_f16(a2, b2f[nt2], acc2[mi][nt2], 0, 0, 0);
    }
  }

  // ---- aggregation via per-wave gather-MFMA (no atomics, no barriers) ----
  // agg[v][d] = sum_e S[v][e] * (acc2[e][d] + eb2[d]),  S[v][e] = valid_e*(dst_e==v)
  {
    float eb2v[8];
    #pragma unroll
    for (int t = 0; t < 8; ++t) eb2v[t] = eb2[t * 16 + ln];
    // write msg^T to per-wave LDS: msgT[col][row], stride 36 halves
    #pragma unroll
    for (int mi = 0; mi < 2; ++mi)
      #pragma unroll
      for (int nt2 = 0; nt2 < 8; ++nt2) {
        half4v pk;
        #pragma unroll
        for (int r = 0; r < 4; ++r)
          pk[r] = (_Float16)(acc2[mi][nt2][r] + eb2v[nt2]);
        *(half4v*)&ws[(nt2 * 16 + ln) * 36 + mi * 16 + quad * 4] = pk;
      }
    // S fragments (A operand): row=ln (node v), k=quad*8+j (edge)
    half8 s0, s1;
    #pragma unroll
    for (int j = 0; j < 8; ++j) {
      int k = quad * 8 + j;
      int dk = sh_edge[2 * k];
      _Float16 vk = (_Float16)sh_valid[wave * 32 + k];
      s0[j] = (dk == ln) ? vk : (_Float16)0.f;
      s1[j] = (ln == 0 && dk == 16) ? vk : (_Float16)0.f;
    }
    f32x4 agg0[8], agg1[8];
    #pragma unroll
    for (int nt2 = 0; nt2 < 8; ++nt2) {
      half8 bfr = *(const half8*)&ws[(nt2 * 16 + ln) * 36 + quad * 8];
      agg0[nt2] = __builtin_amdgcn_mfma_f32_16x16x32_f16(s0, bfr, vzero, 0, 0, 0);
      agg1[nt2] = __builtin_amdgcn_mfma_f32_16x16x32_f16(s1, bfr, vzero, 0, 0, 0);
    }
    float rden[4];
    #pragma unroll
    for (int r = 0; r < 4; ++r)
      rden[r] = 1.f / fmaxf(sh_dn[wave * 20 + quad * 4 + r], 1.f);
    float rden16 = 1.f / fmaxf(sh_dn[wave * 20 + 16], 1.f);
    #pragma unroll
    for (int nt2 = 0; nt2 < 8; ++nt2) {
      #pragma unroll
      for (int r = 0; r < 4; ++r)
        sh_agg16[(wave * 17 + quad * 4 + r) * LDH + nt2 * 16 + ln] =
            (_Float16)(agg0[nt2][r] * rden[r]);
      if (quad == 0)
        sh_agg16[(wave * 17 + 16) * LDH + nt2 * 16 + ln] =
            (_Float16)(agg1[nt2][0] * rden16);
    }
  }
  __syncthreads();                                   // B3: agg16 visible to all waves

  // ================= NODE PHASE (no barriers) =================
  const int Rn = wave * 16 + ln;                     // < 64, always valid
  half8 afn0[8];
  #pragma unroll
  for (int ks = 0; ks < 8; ++ks)
    afn0[ks] = (ks < 4)
        ? *(const half8*)&sh_h16[Rn * LDH + ks * 32 + quad * 8]
        : *(const half8*)&sh_agg16[Rn * LDH + (ks - 4) * 32 + quad * 8];
  half8 afn1[8];                                     // wave 0: tile 4 (rows 64..67)
  if (wave == 0) {
    const int Rx = (64 + ln < 68) ? 64 + ln : 67;
    #pragma unroll
    for (int ks = 0; ks < 8; ++ks)
      afn1[ks] = (ks < 4)
          ? *(const half8*)&sh_h16[Rx * LDH + ks * 32 + quad * 8]
          : *(const half8*)&sh_agg16[Rx * LDH + (ks - 4) * 32 + quad * 8];
  }

  f32x4 acc4a[8], acc4b[8];
  #pragma unroll
  for (int j = 0; j < 8; ++j) { acc4a[j] = vzero; acc4b[j] = vzero; }

  for (int nc = 0; nc < 8; ++nc) {
    half8 b2n[8];
    #pragma unroll
    for (int t = 0; t < 8; ++t)
      b2n[t] = *(const half8*)(nw2img + nc * 4096 + t * 512 + lane * 8);
    float nbv[2];
    #pragma unroll
    for (int nt = 0; nt < 2; ++nt) nbv[nt] = nb1[nc * 32 + nt * 16 + ln];

    f32x4 acc3a[2], acc3b[2];
    acc3a[0] = vzero; acc3a[1] = vzero; acc3b[0] = vzero; acc3b[1] = vzero;

    #pragma unroll
    for (int kc = 0; kc < 8; ++kc) {
      const _Float16* wb = nw1img + (size_t)(nc * 2 + (kc >> 2)) * 4096
                                  + ((kc & 3) * 2) * 512 + lane * 8;
      half8 bf0 = *(const half8*)wb;
      half8 bf1 = *(const half8*)(wb + 512);
      acc3a[0] = __builtin_amdgcn_mfma_f32_16x16x32_f16(afn0[kc], bf0, acc3a[0], 0, 0, 0);
      acc3a[1] = __builtin_amdgcn_mfma_f32_16x16x32_f16(afn0[kc], bf1, acc3a[1], 0, 0, 0);
      if (wave == 0) {
        acc3b[0] = __builtin_amdgcn_mfma_f32_16x16x32_f16(afn1[kc], bf0, acc3b[0], 0, 0, 0);
        acc3b[1] = __builtin_amdgcn_mfma_f32_16x16x32_f16(afn1[kc], bf1, acc3b[1], 0, 0, 0);
      }
    }
    // relu -> myC, then GEMM4 partial-K
    #pragma unroll
    for (int nt = 0; nt < 2; ++nt)
      #pragma unroll
      for (int r = 0; r < 4; ++r)
        ws[(quad * 4 + r) * 40 + nt * 16 + ln] = (_Float16)fmaxf(acc3a[nt][r] + nbv[nt], 0.f);
    if (wave == 0) {
      #pragma unroll
      for (int nt = 0; nt < 2; ++nt)
        #pragma unroll
        for (int r = 0; r < 4; ++r)
          ws[(16 + quad * 4 + r) * 40 + nt * 16 + ln] = (_Float16)fmaxf(acc3b[nt][r] + nbv[nt], 0.f);
    }
    {
      half8 a2 = *(const half8*)&ws[ln * 40 + quad * 8];
      #pragma unroll
      for (int nt2 = 0; nt2 < 8; ++nt2)
        acc4a[nt2] = __builtin_amdgcn_mfma_f32_16x16x32_f16(a2, b2n[nt2], acc4a[nt2], 0, 0, 0);
    }
    if (wave == 0) {
      half8 a2b = *(const half8*)&ws[(16 + ln) * 40 + quad * 8];
      #pragma unroll
      for (int nt2 = 0; nt2 < 8; ++nt2)
        acc4b[nt2] = __builtin_amdgcn_mfma_f32_16x16x32_f16(a2b, b2n[nt2], acc4b[nt2], 0, 0, 0);
    }
  }

  // ---- final epilogue: residual + LayerNorm + mask -> ost -> coalesced store ---
  float gam[8], bet[8], nb2v[8];
  #pragma unroll
  for (int nt2 = 0; nt2 < 8; ++nt2) {
    int d = nt2 * 16 + ln;
    gam[nt2] = gamma[d]; bet[nt2] = beta[d]; nb2v[nt2] = nb2[d];
  }
  __syncthreads();                                   // B4: per-wave scratch -> ost
  float* ost = (float*)uni;
  {
    float xv[8][4];
    #pragma unroll
    for (int nt2 = 0; nt2 < 8; ++nt2) {
      int d = nt2 * 16 + ln;
      #pragma unroll
      for (int r = 0; r < 4; ++r) {
        int R = wave * 16 + quad * 4 + r;
        xv[nt2][r] = (float)sh_h16[R * LDH + d] + (acc4a[nt2][r] + nb2v[nt2]) * sh_hasn[R];
      }
    }
    #pragma unroll
    for (int r = 0; r < 4; ++r) {
      float s = 0.f, s2 = 0.f;
      #pragma unroll
      for (int nt2 = 0; nt2 < 8; ++nt2) { float x = xv[nt2][r]; s += x; s2 += x * x; }
      #pragma unroll
      for (int m = 1; m < 16; m <<= 1) { s += __shfl_xor(s, m, 64); s2 += __shfl_xor(s2, m, 64); }
      float mu = s * (1.f / 128.f);
      float var = s2 * (1.f / 128.f) - mu * mu;
      float rstd = rsqrtf(var + 1e-5f);
      int R = wave * 16 + quad * 4 + r;
      float mk = sh_maskf[R];
      #pragma unroll
      for (int nt2 = 0; nt2 < 8; ++nt2) {
        int d = nt2 * 16 + ln;
        ost[R * 132 + d] = ((xv[nt2][r] - mu) * rstd * gam[nt2] + bet[nt2]) * mk;
      }
    }
  }
  if (wave == 0) {                                   // tile 4: rows 64..67
    float xv[8][4];
    #pragma unroll
    for (int nt2 = 0; nt2 < 8; ++nt2) {
      int d = nt2 * 16 + ln;
      #pragma unroll
      for (int r = 0; r < 4; ++r) {
        int R = 64 + quad * 4 + r;
        int Rc = R < 68 ? R : 67;
        xv[nt2][r] = (float)sh_h16[Rc * LDH + d] + (acc4b[nt2][r] + nb2v[nt2]) * sh_hasn[Rc];
      }
    }
    #pragma unroll
    for (int r = 0; r < 4; ++r) {
      float s = 0.f, s2 = 0.f;
      #pragma unroll
      for (int nt2 = 0; nt2 < 8; ++nt2) { float x = xv[nt2][r]; s += x; s2 += x * x; }
      #pragma unroll
      for (int m = 1; m < 16; m <<= 1) { s += __shfl_xor(s, m, 64); s2 += __shfl_xor(s2, m, 64); }
      float mu = s * (1.f / 128.f);
      float var = s2 * (1.f / 128.f) - mu * mu;
      float rstd = rsqrtf(var + 1e-5f);
      int R = 64 + quad * 4 + r;
      if (R < 68) {
        float mk = sh_maskf[R];
        #pragma unroll
        for (int nt2 = 0; nt2 < 8; ++nt2) {
          int d = nt2 * 16 + ln;
          ost[R * 132 + d] = ((xv[nt2][r] - mu) * rstd * gam[nt2] + bet[nt2]) * mk;
        }
      }
    }
  }
  __syncthreads();                                   // B5
  for (int i = tid; i < 8704; i += 256)
    out[hbase + i] = ost[(i >> 7) * 132 + (i & 127)];
}

extern "C" void kernel_launch(void* const* d_in, const int* in_sizes, int n_in,
                              void* d_out, int out_size, void* d_ws, size_t ws_size,
                              hipStream_t stream) {
  const float* h     = (const float*)d_in[0];
  const float* xy    = (const float*)d_in[1];
  const int*   jm    = (const int*)d_in[2];
  const int*   ei    = (const int*)d_in[3];
  const float* ew1   = (const float*)d_in[4];
  const float* eb1   = (const float*)d_in[5];
  const float* ew2   = (const float*)d_in[6];
  const float* eb2   = (const float*)d_in[7];
  const float* nw1   = (const float*)d_in[8];
  const float* nb1   = (const float*)d_in[9];
  const float* nw2   = (const float*)d_in[10];
  const float* nb2   = (const float*)d_in[11];
  const float* gamma = (const float*)d_in[12];
  const float* beta  = (const float*)d_in[13];
  _Float16* wz = (_Float16*)d_ws;

  prep_weights<<<768, 256, 0, stream>>>(ew1, ew2, nw1, nw2, wz);
  fused_graph_layer<<<4096, 256, 0, stream>>>(h, xy, jm, ei, ew1, eb1, eb2,
                                              nb1, nb2, gamma, beta, wz,
                                              (float*)d_out);
}